// Round 4
// baseline (732.948 us; speedup 1.0000x reference)
//
#include <hip/hip_runtime.h>
#include <stdint.h>
#include <string.h>

#define NLEV 16

typedef float  vfloat4 __attribute__((ext_vector_type(4)));   // nontemporal-store-compatible

// ---------------------------------------------------------------------------
// Shared helpers
// ---------------------------------------------------------------------------
__device__ __forceinline__ void norm_coords(const float* __restrict__ xyz, int p,
                                            float& nx, float& ny, float& nz) {
    const float x = __builtin_nontemporal_load(xyz + 3 * p + 0);
    const float y = __builtin_nontemporal_load(xyz + 3 * p + 1);
    const float z = __builtin_nontemporal_load(xyz + 3 * p + 2);
    const float inv = 1.0f / 1.5f;
    nx = (x + 0.75f) * inv;
    ny = (y + 0.75f) * inv;
    nz = (z + 0.75f) * inv;
}

__device__ __forceinline__ float2 trilerp(const float2 v[8],
                                          float fx, float fy, float fz) {
    const float gx = 1.0f - fx, gy = 1.0f - fy, gz = 1.0f - fz;
    const float w00 = gx * gy, w01 = gx * fy, w10 = fx * gy, w11 = fx * fy;
    float w, f0, f1;
    w = w00 * gz; f0 = w * v[0].x;          f1 = w * v[0].y;
    w = w00 * fz; f0 = fmaf(w, v[1].x, f0); f1 = fmaf(w, v[1].y, f1);
    w = w01 * gz; f0 = fmaf(w, v[2].x, f0); f1 = fmaf(w, v[2].y, f1);
    w = w01 * fz; f0 = fmaf(w, v[3].x, f0); f1 = fmaf(w, v[3].y, f1);
    w = w10 * gz; f0 = fmaf(w, v[4].x, f0); f1 = fmaf(w, v[4].y, f1);
    w = w10 * fz; f0 = fmaf(w, v[5].x, f0); f1 = fmaf(w, v[5].y, f1);
    w = w11 * gz; f0 = fmaf(w, v[6].x, f0); f1 = fmaf(w, v[6].y, f1);
    w = w11 * fz; f0 = fmaf(w, v[7].x, f0); f1 = fmaf(w, v[7].y, f1);
    return make_float2(f0, f1);
}

// ---------------------------------------------------------------------------
// Big levels (7..15): size = 2^19 (pow2 -> 32-bit hash), table = 4 MB = one
// XCD L2. x-pair trick: with x-prime == 1, the 16B float4 chunk at (h0>>1)
// holds both x-corners when bx is even; odd-bx lanes fetch 4 extra float2.
// FOUR points per thread with a depth-3 point pipeline: ~24 gathers
// continuously in flight per thread.
// ---------------------------------------------------------------------------
struct BigPt {
    uint32_t h0[4];
    uint32_t yzs[4];
    uint32_t hx1;
    bool     oddbx;
    float    fx, fy, fz;
    float4   V[4];
    float2   w1[4];
};

template<int R, uint32_t OFF>
__device__ __forceinline__ void big_issue(const float4* __restrict__ emb4,
                                          const float2* __restrict__ emb,
                                          float nx, float ny, float nz, BigPt& s) {
    const uint32_t M = 524287u;
    const float rf = (float)R;
    const float px = nx * rf, py = ny * rf, pz = nz * rf;
    int bx = (int)floorf(px); bx = bx < 0 ? 0 : (bx > R - 1 ? R - 1 : bx);
    int by = (int)floorf(py); by = by < 0 ? 0 : (by > R - 1 ? R - 1 : by);
    int bz = (int)floorf(pz); bz = bz < 0 ? 0 : (bz > R - 1 ? R - 1 : bz);
    s.fx = px - (float)bx;
    s.fy = py - (float)by;
    s.fz = pz - (float)bz;

    const uint32_t hy0 = (uint32_t)by       * 2654435761u;
    const uint32_t hy1 = (uint32_t)(by + 1) * 2654435761u;
    const uint32_t hz0 = (uint32_t)bz       * 805459861u;
    const uint32_t hz1 = (uint32_t)(bz + 1) * 805459861u;
    s.yzs[0] = hy0 ^ hz0; s.yzs[1] = hy0 ^ hz1;
    s.yzs[2] = hy1 ^ hz0; s.yzs[3] = hy1 ^ hz1;

    const uint32_t hx0 = (uint32_t)bx;
    s.oddbx = (bx & 1) != 0;
    s.hx1   = hx0 + 1u;

    #pragma unroll
    for (int i = 0; i < 4; ++i) {
        s.h0[i] = (hx0 ^ s.yzs[i]) & M;
        s.V[i]  = emb4[(s.h0[i] >> 1) + (OFF >> 1)];
    }
    if (s.oddbx) {
        #pragma unroll
        for (int i = 0; i < 4; ++i)
            s.w1[i] = emb[((s.hx1 ^ s.yzs[i]) & M) + OFF];
    }
}

__device__ __forceinline__ float2 big_consume(const BigPt& s) {
    float2 v[8];
    #pragma unroll
    for (int i = 0; i < 4; ++i) {
        const float2 lo = make_float2(s.V[i].x, s.V[i].y);
        const float2 hi = make_float2(s.V[i].z, s.V[i].w);
        const bool oh = (s.h0[i] & 1u) != 0u;
        v[i]     = oh ? hi : lo;
        v[i + 4] = s.oddbx ? s.w1[i] : (oh ? lo : hi);
    }
    return trilerp(v, s.fx, s.fy, s.fz);
}

template<int R, uint32_t OFF>
__global__ __launch_bounds__(256, 4) void big_level4(
    const float* __restrict__ xyz,
    const float2* __restrict__ emb,
    float2* __restrict__ ws,      // level-major slice for this level
    int nb)
{
    const int t    = threadIdx.x;
    const int base = blockIdx.x * 1024 + t;
    const float4* __restrict__ emb4 = (const float4*)emb;

    int p0 = base, p1 = base + 256, p2 = base + 512, p3 = base + 768;
    const int q0 = p0 < nb ? p0 : nb - 1;
    const int q1 = p1 < nb ? p1 : nb - 1;
    const int q2 = p2 < nb ? p2 : nb - 1;
    const int q3 = p3 < nb ? p3 : nb - 1;

    float nx0, ny0, nz0, nx1, ny1, nz1, nx2, ny2, nz2, nx3, ny3, nz3;
    norm_coords(xyz, q0, nx0, ny0, nz0);
    norm_coords(xyz, q1, nx1, ny1, nz1);
    norm_coords(xyz, q2, nx2, ny2, nz2);
    norm_coords(xyz, q3, nx3, ny3, nz3);

    BigPt s0, s1, s2, s3;
    big_issue<R, OFF>(emb4, emb, nx0, ny0, nz0, s0);
    big_issue<R, OFF>(emb4, emb, nx1, ny1, nz1, s1);
    big_issue<R, OFF>(emb4, emb, nx2, ny2, nz2, s2);

    const float2 r0 = big_consume(s0);
    big_issue<R, OFF>(emb4, emb, nx3, ny3, nz3, s3);
    const float2 r1 = big_consume(s1);
    const float2 r2 = big_consume(s2);
    const float2 r3 = big_consume(s3);

    uint64_t u0, u1, u2, u3;
    memcpy(&u0, &r0, 8);
    memcpy(&u1, &r1, 8);
    memcpy(&u2, &r2, 8);
    memcpy(&u3, &r3, 8);
    if (p0 < nb) __builtin_nontemporal_store(u0, (uint64_t*)ws + p0);
    if (p1 < nb) __builtin_nontemporal_store(u1, (uint64_t*)ws + p1);
    if (p2 < nb) __builtin_nontemporal_store(u2, (uint64_t*)ws + p2);
    if (p3 < nb) __builtin_nontemporal_store(u3, (uint64_t*)ws + p3);
}

// ---------------------------------------------------------------------------
// Pack kernel: small levels 0..6 inline (tables 2.47 MB, L2-resident), merge
// big-level results from ws, coalesced output via per-wave LDS transpose.
// 64-thread blocks (8960 B LDS -> 18 blocks/CU, occupancy ceiling 56% vs 50%).
// Depth-3 software pipeline: levels l+1 and l+2 in flight while consuming l
// (24 gather values + 9 ws loads live ≈ 100 VGPR, free: occupancy LDS-capped).
// ---------------------------------------------------------------------------
__global__ __launch_bounds__(64, 4) void pack_small(
    const float* __restrict__ xyz,
    const float2* __restrict__ emb,
    const float2* __restrict__ ws,
    float* __restrict__ out,
    int nb)
{
    constexpr int      kRes[7]  = {16, 20, 25, 32, 40, 50, 64};
    constexpr uint32_t kSize[7] = {4913u, 9261u, 17576u, 35937u, 68921u, 132651u, 274625u};
    constexpr uint32_t kOff[7]  = {0u, 4913u, 14174u, 31750u, 67687u, 136608u, 269259u};

    __shared__ __align__(16) float lds[64 * 35];

    const int lane = threadIdx.x;
    const int p    = blockIdx.x * 64 + lane;
    const int pc   = (p < nb) ? p : (nb - 1);

    // hoist big-level ws loads: 9 HBM reads in flight during all small levels
    uint64_t wsv[9];
    #pragma unroll
    for (int l = 0; l < 9; ++l)
        wsv[l] = __builtin_nontemporal_load(
            (const uint64_t*)ws + (size_t)l * nb + pc);

    const float x = xyz[3 * pc + 0];
    const float y = xyz[3 * pc + 1];
    const float z = xyz[3 * pc + 2];

    float* wl = &lds[lane * 35];
    wl[0] = x; wl[1] = y; wl[2] = z;

    const float inv = 1.0f / 1.5f;
    const float nx = (x + 0.75f) * inv;
    const float ny = (y + 0.75f) * inv;
    const float nz = (z + 0.75f) * inv;

    uint32_t idx[3][8];
    float2   v[3][8];
    float    fr[3][3];

    // index computation for one level (lv is a constant after unroll)
    auto level_idx = [&](int lv, uint32_t (&ix)[8], float (&f)[3]) {
        const int      r   = kRes[lv];
        const float    rf  = (float)r;
        const uint32_t sz  = kSize[lv];
        const uint32_t off = kOff[lv];

        const float px = nx * rf, py = ny * rf, pz = nz * rf;
        int bx = (int)floorf(px); bx = bx < 0 ? 0 : (bx > r - 1 ? r - 1 : bx);
        int by = (int)floorf(py); by = by < 0 ? 0 : (by > r - 1 ? r - 1 : by);
        int bz = (int)floorf(pz); bz = bz < 0 ? 0 : (bz > r - 1 ? r - 1 : bz);
        f[0] = px - (float)bx;
        f[1] = py - (float)by;
        f[2] = pz - (float)bz;

        const uint64_t hx0 = (uint64_t)(uint32_t)bx;
        const uint64_t hx1 = hx0 + 1u;
        const uint64_t hy0 = (uint64_t)(uint32_t)by       * 2654435761ull;
        const uint64_t hy1 = (uint64_t)(uint32_t)(by + 1) * 2654435761ull;
        const uint64_t hz0 = (uint64_t)(uint32_t)bz       * 805459861ull;
        const uint64_t hz1 = (uint64_t)(uint32_t)(bz + 1) * 805459861ull;

        const uint64_t yz00 = hy0 ^ hz0, yz01 = hy0 ^ hz1;
        const uint64_t yz10 = hy1 ^ hz0, yz11 = hy1 ^ hz1;

        ix[0] = (uint32_t)((hx0 ^ yz00) % sz) + off;
        ix[1] = (uint32_t)((hx0 ^ yz01) % sz) + off;
        ix[2] = (uint32_t)((hx0 ^ yz10) % sz) + off;
        ix[3] = (uint32_t)((hx0 ^ yz11) % sz) + off;
        ix[4] = (uint32_t)((hx1 ^ yz00) % sz) + off;
        ix[5] = (uint32_t)((hx1 ^ yz01) % sz) + off;
        ix[6] = (uint32_t)((hx1 ^ yz10) % sz) + off;
        ix[7] = (uint32_t)((hx1 ^ yz11) % sz) + off;
    };

    // prologue: levels 0 and 1 in flight
    level_idx(0, idx[0], fr[0]);
    #pragma unroll
    for (int i = 0; i < 8; ++i) v[0][i] = emb[idx[0][i]];
    level_idx(1, idx[1], fr[1]);
    #pragma unroll
    for (int i = 0; i < 8; ++i) v[1][i] = emb[idx[1][i]];

    #pragma unroll
    for (int l = 0; l < 7; ++l) {
        const int cur = l % 3;
        if (l < 5) {
            const int nxt = (l + 2) % 3;
            level_idx(l + 2, idx[nxt], fr[nxt]);
            #pragma unroll
            for (int i = 0; i < 8; ++i) v[nxt][i] = emb[idx[nxt][i]];
        }
        const float2 rr = trilerp(v[cur], fr[cur][0], fr[cur][1], fr[cur][2]);
        wl[3 + 2 * l] = rr.x;
        wl[4 + 2 * l] = rr.y;
    }

    // big-level results (in flight since kernel start)
    #pragma unroll
    for (int l = 0; l < 9; ++l) {
        float2 bv;
        memcpy(&bv, &wsv[l], 8);
        wl[3 + 2 * (l + 7)] = bv.x;
        wl[4 + 2 * (l + 7)] = bv.y;
    }

    __syncthreads();

    if (blockIdx.x * 64 < nb) {
        // linear copy of the wave's 64 records (8960 B), float4-wide,
        // nontemporal so the 140 MB output stream doesn't evict small tables
        const vfloat4* s4 = (const vfloat4*)lds;
        vfloat4* d4 = (vfloat4*)(out + (size_t)blockIdx.x * (64 * 35));
        #pragma unroll
        for (int c = 0; c < 8; ++c)
            __builtin_nontemporal_store(s4[c * 64 + lane], &d4[c * 64 + lane]);
        if (lane < 48)
            __builtin_nontemporal_store(s4[8 * 64 + lane], &d4[8 * 64 + lane]);
    }
}

// ---------------------------------------------------------------------------
// Fallback: monolithic kernel (used only if ws_size < 72 MB)
// ---------------------------------------------------------------------------
__global__ __launch_bounds__(256, 4) void hashgrid_mono(
    const float* __restrict__ xyz,
    const float2* __restrict__ emb,
    float* __restrict__ out,
    int nb)
{
    constexpr int      kRes[NLEV]  = {16,20,25,32,40,50,64,80,101,128,161,203,256,322,406,512};
    constexpr uint32_t kSize[NLEV] = {4913u,9261u,17576u,35937u,68921u,132651u,274625u,
                                      524288u,524288u,524288u,524288u,524288u,
                                      524288u,524288u,524288u,524288u};
    constexpr uint32_t kOff[NLEV]  = {0u,4913u,14174u,31750u,67687u,136608u,269259u,543884u,
                                      1068172u,1592460u,2116748u,2641036u,3165324u,
                                      3689612u,4213900u,4738188u};

    __shared__ __align__(16) float lds[4 * 64 * 35];

    const int tid  = threadIdx.x;
    const int lane = tid & 63;
    const int wid  = tid >> 6;
    const int p    = blockIdx.x * 256 + tid;
    const int pc   = (p < nb) ? p : (nb - 1);

    const float x = xyz[3 * pc + 0];
    const float y = xyz[3 * pc + 1];
    const float z = xyz[3 * pc + 2];

    float* wl = &lds[(wid * 64 + lane) * 35];
    wl[0] = x; wl[1] = y; wl[2] = z;

    const float inv = 1.0f / 1.5f;
    const float nx = (x + 0.75f) * inv;
    const float ny = (y + 0.75f) * inv;
    const float nz = (z + 0.75f) * inv;

    #pragma unroll
    for (int l = 0; l < NLEV; ++l) {
        const int      r   = kRes[l];
        const float    rf  = (float)r;
        const uint32_t sz  = kSize[l];
        const uint32_t off = kOff[l];

        const float px = nx * rf, py = ny * rf, pz = nz * rf;
        int bx = (int)floorf(px); bx = bx < 0 ? 0 : (bx > r - 1 ? r - 1 : bx);
        int by = (int)floorf(py); by = by < 0 ? 0 : (by > r - 1 ? r - 1 : by);
        int bz = (int)floorf(pz); bz = bz < 0 ? 0 : (bz > r - 1 ? r - 1 : bz);
        const float fx = px - (float)bx;
        const float fy = py - (float)by;
        const float fz = pz - (float)bz;

        const uint64_t hx0 = (uint64_t)(uint32_t)bx;
        const uint64_t hx1 = hx0 + 1u;
        const uint64_t hy0 = (uint64_t)(uint32_t)by       * 2654435761ull;
        const uint64_t hy1 = (uint64_t)(uint32_t)(by + 1) * 2654435761ull;
        const uint64_t hz0 = (uint64_t)(uint32_t)bz       * 805459861ull;
        const uint64_t hz1 = (uint64_t)(uint32_t)(bz + 1) * 805459861ull;

        const uint64_t yz00 = hy0 ^ hz0, yz01 = hy0 ^ hz1;
        const uint64_t yz10 = hy1 ^ hz0, yz11 = hy1 ^ hz1;

        const uint32_t i000 = (uint32_t)((hx0 ^ yz00) % sz) + off;
        const uint32_t i001 = (uint32_t)((hx0 ^ yz01) % sz) + off;
        const uint32_t i010 = (uint32_t)((hx0 ^ yz10) % sz) + off;
        const uint32_t i011 = (uint32_t)((hx0 ^ yz11) % sz) + off;
        const uint32_t i100 = (uint32_t)((hx1 ^ yz00) % sz) + off;
        const uint32_t i101 = (uint32_t)((hx1 ^ yz01) % sz) + off;
        const uint32_t i110 = (uint32_t)((hx1 ^ yz10) % sz) + off;
        const uint32_t i111 = (uint32_t)((hx1 ^ yz11) % sz) + off;

        const float2 v000 = emb[i000];
        const float2 v001 = emb[i001];
        const float2 v010 = emb[i010];
        const float2 v011 = emb[i011];
        const float2 v100 = emb[i100];
        const float2 v101 = emb[i101];
        const float2 v110 = emb[i110];
        const float2 v111 = emb[i111];

        const float gx = 1.0f - fx, gy = 1.0f - fy, gz = 1.0f - fz;
        const float w00 = gx * gy, w01 = gx * fy, w10 = fx * gy, w11 = fx * fy;

        float w, f0, f1;
        w = w00 * gz; f0 = w * v000.x;          f1 = w * v000.y;
        w = w00 * fz; f0 = fmaf(w, v001.x, f0); f1 = fmaf(w, v001.y, f1);
        w = w01 * gz; f0 = fmaf(w, v010.x, f0); f1 = fmaf(w, v010.y, f1);
        w = w01 * fz; f0 = fmaf(w, v011.x, f0); f1 = fmaf(w, v011.y, f1);
        w = w10 * gz; f0 = fmaf(w, v100.x, f0); f1 = fmaf(w, v100.y, f1);
        w = w10 * fz; f0 = fmaf(w, v101.x, f0); f1 = fmaf(w, v101.y, f1);
        w = w11 * gz; f0 = fmaf(w, v110.x, f0); f1 = fmaf(w, v110.y, f1);
        w = w11 * fz; f0 = fmaf(w, v111.x, f0); f1 = fmaf(w, v111.y, f1);

        wl[3 + 2 * l] = f0;
        wl[4 + 2 * l] = f1;
    }

    __syncthreads();

    const int wave_gid = blockIdx.x * 4 + wid;
    if (wave_gid * 64 < nb) {
        const float* src = &lds[wid * 64 * 35];
        float* dst = out + (size_t)wave_gid * (64 * 35);
        #pragma unroll
        for (int c = 0; c < 35; ++c)
            dst[c * 64 + lane] = src[c * 64 + lane];
    }
}

// ---------------------------------------------------------------------------
extern "C" void kernel_launch(void* const* d_in, const int* in_sizes, int n_in,
                              void* d_out, int out_size, void* d_ws, size_t ws_size,
                              hipStream_t stream) {
    const float*  xyz = (const float*)d_in[0];
    const float2* emb = (const float2*)d_in[1];
    float*        out = (float*)d_out;
    const int nb = in_sizes[0] / 3;             // 1,000,000
    const int blocksP = (nb + 63) / 64;         // 15625 (pack, 1 wave/block)
    const int blocksB = (nb + 1023) / 1024;     // 977   (big levels, 4 pts/thread)

    const size_t ws_need = (size_t)9 * (size_t)nb * sizeof(float2);  // 72 MB
    if (ws_size < ws_need) {
        const int blocksM = (nb + 255) / 256;
        hashgrid_mono<<<blocksM, 256, 0, stream>>>(xyz, emb, out, nb);
        return;
    }

    float2* ws = (float2*)d_ws;
    // levels 7..15: R = {80,101,128,161,203,256,322,406,512}
    big_level4< 80,  543884u><<<blocksB, 256, 0, stream>>>(xyz, emb, ws + (size_t)0 * nb, nb);
    big_level4<101, 1068172u><<<blocksB, 256, 0, stream>>>(xyz, emb, ws + (size_t)1 * nb, nb);
    big_level4<128, 1592460u><<<blocksB, 256, 0, stream>>>(xyz, emb, ws + (size_t)2 * nb, nb);
    big_level4<161, 2116748u><<<blocksB, 256, 0, stream>>>(xyz, emb, ws + (size_t)3 * nb, nb);
    big_level4<203, 2641036u><<<blocksB, 256, 0, stream>>>(xyz, emb, ws + (size_t)4 * nb, nb);
    big_level4<256, 3165324u><<<blocksB, 256, 0, stream>>>(xyz, emb, ws + (size_t)5 * nb, nb);
    big_level4<322, 3689612u><<<blocksB, 256, 0, stream>>>(xyz, emb, ws + (size_t)6 * nb, nb);
    big_level4<406, 4213900u><<<blocksB, 256, 0, stream>>>(xyz, emb, ws + (size_t)7 * nb, nb);
    big_level4<512, 4738188u><<<blocksB, 256, 0, stream>>>(xyz, emb, ws + (size_t)8 * nb, nb);
    pack_small<<<blocksP, 64, 0, stream>>>(xyz, emb, ws, out, nb);
}

// Round 5
// 584.672 us; speedup vs baseline: 1.2536x; 1.2536x over previous
//
#include <hip/hip_runtime.h>
#include <stdint.h>
#include <string.h>

#define NLEV 16

typedef float  vfloat4 __attribute__((ext_vector_type(4)));   // nontemporal-store-compatible

// ---------------------------------------------------------------------------
// Shared helpers
// ---------------------------------------------------------------------------
__device__ __forceinline__ void norm_coords(const float* __restrict__ xyz, int p,
                                            float& nx, float& ny, float& nz) {
    const float x = __builtin_nontemporal_load(xyz + 3 * p + 0);
    const float y = __builtin_nontemporal_load(xyz + 3 * p + 1);
    const float z = __builtin_nontemporal_load(xyz + 3 * p + 2);
    const float inv = 1.0f / 1.5f;
    nx = (x + 0.75f) * inv;
    ny = (y + 0.75f) * inv;
    nz = (z + 0.75f) * inv;
}

__device__ __forceinline__ float2 trilerp(const float2 v[8],
                                          float fx, float fy, float fz) {
    const float gx = 1.0f - fx, gy = 1.0f - fy, gz = 1.0f - fz;
    const float w00 = gx * gy, w01 = gx * fy, w10 = fx * gy, w11 = fx * fy;
    float w, f0, f1;
    w = w00 * gz; f0 = w * v[0].x;          f1 = w * v[0].y;
    w = w00 * fz; f0 = fmaf(w, v[1].x, f0); f1 = fmaf(w, v[1].y, f1);
    w = w01 * gz; f0 = fmaf(w, v[2].x, f0); f1 = fmaf(w, v[2].y, f1);
    w = w01 * fz; f0 = fmaf(w, v[3].x, f0); f1 = fmaf(w, v[3].y, f1);
    w = w10 * gz; f0 = fmaf(w, v[4].x, f0); f1 = fmaf(w, v[4].y, f1);
    w = w10 * fz; f0 = fmaf(w, v[5].x, f0); f1 = fmaf(w, v[5].y, f1);
    w = w11 * gz; f0 = fmaf(w, v[6].x, f0); f1 = fmaf(w, v[6].y, f1);
    w = w11 * fz; f0 = fmaf(w, v[7].x, f0); f1 = fmaf(w, v[7].y, f1);
    return make_float2(f0, f1);
}

// ---------------------------------------------------------------------------
// Big levels (7..15), ROUND-3 VERSION (measured best: ~46 us/level).
// size = 2^19 (pow2 -> 32-bit hash), table = 4 MB = one XCD L2. x-pair trick:
// with x-prime == 1, the 16B-aligned float4 chunk at (h0>>1) holds both
// x-corners when bx is even; odd-bx lanes fetch 4 extra float2.
// Two points per thread. 4-pt version spilled (round 4 regression) — keep 2.
// ---------------------------------------------------------------------------
template<int R, uint32_t OFF>
__global__ __launch_bounds__(256, 4) void big_level2(
    const float* __restrict__ xyz,
    const float2* __restrict__ emb,
    float2* __restrict__ ws,      // level-major slice for this level
    int nb)
{
    const int t  = threadIdx.x;
    const int p0 = blockIdx.x * 512 + t;
    const int p1 = p0 + 256;
    const int q[2] = { p0 < nb ? p0 : nb - 1, p1 < nb ? p1 : nb - 1 };

    const float4* __restrict__ emb4 = (const float4*)emb;
    const uint32_t M = 524287u;

    uint32_t h0[2][4];
    uint32_t yzs[2][4];
    uint32_t hx1_[2];
    float4   V[2][4];
    float2   w1[2][4];
    float    fx[2], fy[2], fz[2];
    bool     oddbx[2];

    // phase 1: address math + issue all float4 chunk loads (8 in flight)
    #pragma unroll
    for (int j = 0; j < 2; ++j) {
        float nx, ny, nz;
        norm_coords(xyz, q[j], nx, ny, nz);
        const float rf = (float)R;
        const float px = nx * rf, py = ny * rf, pz = nz * rf;
        int bx = (int)floorf(px); bx = bx < 0 ? 0 : (bx > R - 1 ? R - 1 : bx);
        int by = (int)floorf(py); by = by < 0 ? 0 : (by > R - 1 ? R - 1 : by);
        int bz = (int)floorf(pz); bz = bz < 0 ? 0 : (bz > R - 1 ? R - 1 : bz);
        fx[j] = px - (float)bx;
        fy[j] = py - (float)by;
        fz[j] = pz - (float)bz;

        const uint32_t hy0 = (uint32_t)by       * 2654435761u;
        const uint32_t hy1 = (uint32_t)(by + 1) * 2654435761u;
        const uint32_t hz0 = (uint32_t)bz       * 805459861u;
        const uint32_t hz1 = (uint32_t)(bz + 1) * 805459861u;
        yzs[j][0] = hy0 ^ hz0; yzs[j][1] = hy0 ^ hz1;
        yzs[j][2] = hy1 ^ hz0; yzs[j][3] = hy1 ^ hz1;

        const uint32_t hx0 = (uint32_t)bx;
        oddbx[j] = (bx & 1) != 0;
        hx1_[j]  = hx0 + 1u;

        #pragma unroll
        for (int i = 0; i < 4; ++i) {
            h0[j][i] = (hx0 ^ yzs[j][i]) & M;
            V[j][i]  = emb4[(h0[j][i] >> 1) + (OFF >> 1)];
        }
    }

    // phase 2: odd-bx lanes fetch the 4 x1-corners they can't get from chunks
    #pragma unroll
    for (int j = 0; j < 2; ++j) {
        if (oddbx[j]) {
            #pragma unroll
            for (int i = 0; i < 4; ++i)
                w1[j][i] = emb[((hx1_[j] ^ yzs[j][i]) & M) + OFF];
        }
    }

    // phase 3: select halves + interpolate
    float2 r[2];
    #pragma unroll
    for (int j = 0; j < 2; ++j) {
        float2 v[8];
        #pragma unroll
        for (int i = 0; i < 4; ++i) {
            const float2 lo = make_float2(V[j][i].x, V[j][i].y);
            const float2 hi = make_float2(V[j][i].z, V[j][i].w);
            const bool oh = (h0[j][i] & 1u) != 0u;
            v[i]     = oh ? hi : lo;
            v[i + 4] = oddbx[j] ? w1[j][i] : (oh ? lo : hi);
        }
        r[j] = trilerp(v, fx[j], fy[j], fz[j]);
    }

    uint64_t u0, u1;
    memcpy(&u0, &r[0], 8);
    memcpy(&u1, &r[1], 8);
    if (p0 < nb) __builtin_nontemporal_store(u0, (uint64_t*)ws + p0);
    if (p1 < nb) __builtin_nontemporal_store(u1, (uint64_t*)ws + p1);
}

// ---------------------------------------------------------------------------
// Pack kernel (256-thread blocks, round-3 structure): small levels 0..6
// inline, merge big-level ws, coalesced out via per-wave LDS transpose.
// NEW: x-pair trick generalized to mod-sized tables. When bx is even the two
// x-corner pre-mod hashes are consecutive integers {amin, amin+1}, so their
// post-mod indices are consecutive (barring wrap): ONE 16B load covers both
// corners. Only odd-bx / wrap lanes issue the extra float2 (≈51%).
// Lane-requests per point-level: 8 -> ~6.
// ---------------------------------------------------------------------------
__global__ __launch_bounds__(256, 4) void pack_small(
    const float* __restrict__ xyz,
    const float2* __restrict__ emb,
    const float2* __restrict__ ws,
    float* __restrict__ out,
    int nb)
{
    constexpr int      kRes[7]  = {16, 20, 25, 32, 40, 50, 64};
    constexpr uint32_t kSize[7] = {4913u, 9261u, 17576u, 35937u, 68921u, 132651u, 274625u};
    constexpr uint32_t kOff[7]  = {0u, 4913u, 14174u, 31750u, 67687u, 136608u, 269259u};

    __shared__ __align__(16) float lds[4 * 64 * 35];

    const int tid  = threadIdx.x;
    const int lane = tid & 63;
    const int wid  = tid >> 6;
    const int p    = blockIdx.x * 256 + tid;
    const int pc   = (p < nb) ? p : (nb - 1);

    // hoist big-level ws loads: 9 HBM reads in flight during all small levels
    uint64_t wsv[9];
    #pragma unroll
    for (int l = 0; l < 9; ++l)
        wsv[l] = __builtin_nontemporal_load(
            (const uint64_t*)ws + (size_t)l * nb + pc);

    const float x = xyz[3 * pc + 0];
    const float y = xyz[3 * pc + 1];
    const float z = xyz[3 * pc + 2];

    float* wl = &lds[(wid * 64 + lane) * 35];
    wl[0] = x; wl[1] = y; wl[2] = z;

    const float inv = 1.0f / 1.5f;
    const float nx = (x + 0.75f) * inv;
    const float ny = (y + 0.75f) * inv;
    const float nz = (z + 0.75f) * inv;

    #pragma unroll
    for (int l = 0; l < 7; ++l) {
        const int      r   = kRes[l];
        const float    rf  = (float)r;
        const uint32_t sz  = kSize[l];
        const uint32_t off = kOff[l];

        const float px = nx * rf, py = ny * rf, pz = nz * rf;
        int bx = (int)floorf(px); bx = bx < 0 ? 0 : (bx > r - 1 ? r - 1 : bx);
        int by = (int)floorf(py); by = by < 0 ? 0 : (by > r - 1 ? r - 1 : by);
        int bz = (int)floorf(pz); bz = bz < 0 ? 0 : (bz > r - 1 ? r - 1 : bz);
        const float fx = px - (float)bx;
        const float fy = py - (float)by;
        const float fz = pz - (float)bz;

        const bool     evenbx = (bx & 1) == 0;
        const uint64_t hx0 = (uint64_t)(uint32_t)bx;
        const uint64_t hx1 = hx0 + 1u;
        const uint64_t hy0 = (uint64_t)(uint32_t)by       * 2654435761ull;
        const uint64_t hy1 = (uint64_t)(uint32_t)(by + 1) * 2654435761ull;
        const uint64_t hz0 = (uint64_t)(uint32_t)bz       * 805459861ull;
        const uint64_t hz1 = (uint64_t)(uint32_t)(bz + 1) * 805459861ull;

        const uint64_t yzc[4] = { hy0 ^ hz0, hy0 ^ hz1, hy1 ^ hz0, hy1 ^ hz1 };

        float2 v[8];
        #pragma unroll
        for (int c = 0; c < 4; ++c) {
            const uint64_t a0 = hx0 ^ yzc[c];          // x0 pre-mod hash
            const uint32_t h0 = (uint32_t)(a0 % sz);   // x0 table slot
            const bool     odd_a = ((uint32_t)a0 & 1u) != 0u;
            // amin = a0 & ~1; amin % sz = h0 - (a0&1)  (or wraps to sz-1 -> reject)
            const int  hm = (int)h0 - (int)(odd_a ? 1 : 0);
            const bool ok = evenbx && (hm >= 0) && (hm != (int)sz - 1);
            const uint32_t iload = (ok ? (uint32_t)hm : h0) + off;
            // 16B load covers table slots iload, iload+1 (8B-aligned dwordx4)
            const float4 V = *(const float4*)(emb + iload);
            float2 w1 = make_float2(0.0f, 0.0f);
            if (!ok) {
                const uint32_t h1 = (uint32_t)((hx1 ^ yzc[c]) % sz);
                w1 = emb[h1 + off];
            }
            const float2 loV = make_float2(V.x, V.y);
            const float2 hiV = make_float2(V.z, V.w);
            v[c]     = ok ? (odd_a ? hiV : loV) : loV;   // x0 corner
            v[c + 4] = ok ? (odd_a ? loV : hiV) : w1;    // x1 corner
        }

        const float2 rr = trilerp(v, fx, fy, fz);
        wl[3 + 2 * l] = rr.x;
        wl[4 + 2 * l] = rr.y;
    }

    // big-level results (in flight since kernel start)
    #pragma unroll
    for (int l = 0; l < 9; ++l) {
        float2 bv;
        memcpy(&bv, &wsv[l], 8);
        wl[3 + 2 * (l + 7)] = bv.x;
        wl[4 + 2 * (l + 7)] = bv.y;
    }

    __syncthreads();

    const int wave_gid = blockIdx.x * 4 + wid;
    if (wave_gid * 64 < nb) {
        // linear copy of the wave's 64 records (8960 B), float4-wide,
        // nontemporal so the 140 MB output stream doesn't evict small tables
        const vfloat4* s4 = (const vfloat4*)&lds[wid * 64 * 35];
        vfloat4* d4 = (vfloat4*)(out + (size_t)wave_gid * (64 * 35));
        #pragma unroll
        for (int c = 0; c < 8; ++c)
            __builtin_nontemporal_store(s4[c * 64 + lane], &d4[c * 64 + lane]);
        if (lane < 48)
            __builtin_nontemporal_store(s4[8 * 64 + lane], &d4[8 * 64 + lane]);
    }
}

// ---------------------------------------------------------------------------
// Fallback: monolithic kernel (used only if ws_size < 72 MB)
// ---------------------------------------------------------------------------
__global__ __launch_bounds__(256, 4) void hashgrid_mono(
    const float* __restrict__ xyz,
    const float2* __restrict__ emb,
    float* __restrict__ out,
    int nb)
{
    constexpr int      kRes[NLEV]  = {16,20,25,32,40,50,64,80,101,128,161,203,256,322,406,512};
    constexpr uint32_t kSize[NLEV] = {4913u,9261u,17576u,35937u,68921u,132651u,274625u,
                                      524288u,524288u,524288u,524288u,524288u,
                                      524288u,524288u,524288u,524288u};
    constexpr uint32_t kOff[NLEV]  = {0u,4913u,14174u,31750u,67687u,136608u,269259u,543884u,
                                      1068172u,1592460u,2116748u,2641036u,3165324u,
                                      3689612u,4213900u,4738188u};

    __shared__ __align__(16) float lds[4 * 64 * 35];

    const int tid  = threadIdx.x;
    const int lane = tid & 63;
    const int wid  = tid >> 6;
    const int p    = blockIdx.x * 256 + tid;
    const int pc   = (p < nb) ? p : (nb - 1);

    const float x = xyz[3 * pc + 0];
    const float y = xyz[3 * pc + 1];
    const float z = xyz[3 * pc + 2];

    float* wl = &lds[(wid * 64 + lane) * 35];
    wl[0] = x; wl[1] = y; wl[2] = z;

    const float inv = 1.0f / 1.5f;
    const float nx = (x + 0.75f) * inv;
    const float ny = (y + 0.75f) * inv;
    const float nz = (z + 0.75f) * inv;

    #pragma unroll
    for (int l = 0; l < NLEV; ++l) {
        const int      r   = kRes[l];
        const float    rf  = (float)r;
        const uint32_t sz  = kSize[l];
        const uint32_t off = kOff[l];

        const float px = nx * rf, py = ny * rf, pz = nz * rf;
        int bx = (int)floorf(px); bx = bx < 0 ? 0 : (bx > r - 1 ? r - 1 : bx);
        int by = (int)floorf(py); by = by < 0 ? 0 : (by > r - 1 ? r - 1 : by);
        int bz = (int)floorf(pz); bz = bz < 0 ? 0 : (bz > r - 1 ? r - 1 : bz);
        const float fx = px - (float)bx;
        const float fy = py - (float)by;
        const float fz = pz - (float)bz;

        const uint64_t hx0 = (uint64_t)(uint32_t)bx;
        const uint64_t hx1 = hx0 + 1u;
        const uint64_t hy0 = (uint64_t)(uint32_t)by       * 2654435761ull;
        const uint64_t hy1 = (uint64_t)(uint32_t)(by + 1) * 2654435761ull;
        const uint64_t hz0 = (uint64_t)(uint32_t)bz       * 805459861ull;
        const uint64_t hz1 = (uint64_t)(uint32_t)(bz + 1) * 805459861ull;

        const uint64_t yz00 = hy0 ^ hz0, yz01 = hy0 ^ hz1;
        const uint64_t yz10 = hy1 ^ hz0, yz11 = hy1 ^ hz1;

        const uint32_t i000 = (uint32_t)((hx0 ^ yz00) % sz) + off;
        const uint32_t i001 = (uint32_t)((hx0 ^ yz01) % sz) + off;
        const uint32_t i010 = (uint32_t)((hx0 ^ yz10) % sz) + off;
        const uint32_t i011 = (uint32_t)((hx0 ^ yz11) % sz) + off;
        const uint32_t i100 = (uint32_t)((hx1 ^ yz00) % sz) + off;
        const uint32_t i101 = (uint32_t)((hx1 ^ yz01) % sz) + off;
        const uint32_t i110 = (uint32_t)((hx1 ^ yz10) % sz) + off;
        const uint32_t i111 = (uint32_t)((hx1 ^ yz11) % sz) + off;

        const float2 v000 = emb[i000];
        const float2 v001 = emb[i001];
        const float2 v010 = emb[i010];
        const float2 v011 = emb[i011];
        const float2 v100 = emb[i100];
        const float2 v101 = emb[i101];
        const float2 v110 = emb[i110];
        const float2 v111 = emb[i111];

        const float gx = 1.0f - fx, gy = 1.0f - fy, gz = 1.0f - fz;
        const float w00 = gx * gy, w01 = gx * fy, w10 = fx * gy, w11 = fx * fy;

        float w, f0, f1;
        w = w00 * gz; f0 = w * v000.x;          f1 = w * v000.y;
        w = w00 * fz; f0 = fmaf(w, v001.x, f0); f1 = fmaf(w, v001.y, f1);
        w = w01 * gz; f0 = fmaf(w, v010.x, f0); f1 = fmaf(w, v010.y, f1);
        w = w01 * fz; f0 = fmaf(w, v011.x, f0); f1 = fmaf(w, v011.y, f1);
        w = w10 * gz; f0 = fmaf(w, v100.x, f0); f1 = fmaf(w, v100.y, f1);
        w = w10 * fz; f0 = fmaf(w, v101.x, f0); f1 = fmaf(w, v101.y, f1);
        w = w11 * gz; f0 = fmaf(w, v110.x, f0); f1 = fmaf(w, v110.y, f1);
        w = w11 * fz; f0 = fmaf(w, v111.x, f0); f1 = fmaf(w, v111.y, f1);

        wl[3 + 2 * l] = f0;
        wl[4 + 2 * l] = f1;
    }

    __syncthreads();

    const int wave_gid = blockIdx.x * 4 + wid;
    if (wave_gid * 64 < nb) {
        const float* src = &lds[wid * 64 * 35];
        float* dst = out + (size_t)wave_gid * (64 * 35);
        #pragma unroll
        for (int c = 0; c < 35; ++c)
            dst[c * 64 + lane] = src[c * 64 + lane];
    }
}

// ---------------------------------------------------------------------------
extern "C" void kernel_launch(void* const* d_in, const int* in_sizes, int n_in,
                              void* d_out, int out_size, void* d_ws, size_t ws_size,
                              hipStream_t stream) {
    const float*  xyz = (const float*)d_in[0];
    const float2* emb = (const float2*)d_in[1];
    float*        out = (float*)d_out;
    const int nb = in_sizes[0] / 3;             // 1,000,000
    const int blocks  = (nb + 255) / 256;       // 3907  (pack)
    const int blocks2 = (nb + 511) / 512;       // 1954  (big levels, 2 pts/thread)

    const size_t ws_need = (size_t)9 * (size_t)nb * sizeof(float2);  // 72 MB
    if (ws_size < ws_need) {
        hashgrid_mono<<<blocks, 256, 0, stream>>>(xyz, emb, out, nb);
        return;
    }

    float2* ws = (float2*)d_ws;
    // levels 7..15: R = {80,101,128,161,203,256,322,406,512}
    big_level2< 80,  543884u><<<blocks2, 256, 0, stream>>>(xyz, emb, ws + (size_t)0 * nb, nb);
    big_level2<101, 1068172u><<<blocks2, 256, 0, stream>>>(xyz, emb, ws + (size_t)1 * nb, nb);
    big_level2<128, 1592460u><<<blocks2, 256, 0, stream>>>(xyz, emb, ws + (size_t)2 * nb, nb);
    big_level2<161, 2116748u><<<blocks2, 256, 0, stream>>>(xyz, emb, ws + (size_t)3 * nb, nb);
    big_level2<203, 2641036u><<<blocks2, 256, 0, stream>>>(xyz, emb, ws + (size_t)4 * nb, nb);
    big_level2<256, 3165324u><<<blocks2, 256, 0, stream>>>(xyz, emb, ws + (size_t)5 * nb, nb);
    big_level2<322, 3689612u><<<blocks2, 256, 0, stream>>>(xyz, emb, ws + (size_t)6 * nb, nb);
    big_level2<406, 4213900u><<<blocks2, 256, 0, stream>>>(xyz, emb, ws + (size_t)7 * nb, nb);
    big_level2<512, 4738188u><<<blocks2, 256, 0, stream>>>(xyz, emb, ws + (size_t)8 * nb, nb);
    pack_small<<<blocks, 256, 0, stream>>>(xyz, emb, ws, out, nb);
}